// Round 14
// baseline (523.813 us; speedup 1.0000x reference)
//
#include <hip/hip_runtime.h>
#include <hip/hip_bf16.h>

// Problem constants
constexpr int BB = 2, PP = 64, NN = 256, CC = 512, HH = 8, HD = 64, MLPD = 2048;
constexpr int BP = BB * PP;       // 128
constexpr int MTOT = BP * NN;     // 32768
constexpr float EPS = 1e-5f;

typedef __attribute__((ext_vector_type(8))) short short8_t;
typedef __attribute__((ext_vector_type(4))) short short4_t;
typedef __attribute__((ext_vector_type(4))) float f32x4_t;
typedef __attribute__((ext_vector_type(2))) unsigned int uint2_t;

__device__ inline unsigned short f2bf(float f) {
  union { float f; unsigned u; } v; v.f = f;
  unsigned r = v.u + 0x7fffu + ((v.u >> 16) & 1u);
  return (unsigned short)(r >> 16);
}
__device__ inline float bf2f(unsigned short u) {
  union { unsigned u; float f; } v; v.u = ((unsigned)u) << 16;
  return v.f;
}
// pack 2 f32 -> 2 bf16 in one dword (RNE), gfx950 HW op
__device__ inline unsigned int cvt_pk_bf16(float lo, float hi) {
  unsigned int r;
  asm("v_cvt_pk_bf16_f32 %0, %1, %2" : "=v"(r) : "v"(lo), "v"(hi));
  return r;
}

// async 16B global -> LDS (wave-uniform LDS base, per-lane global addr; HW writes base + lane*16)
__device__ inline void async_copy16(unsigned short* lds_base, const unsigned short* g) {
  __builtin_amdgcn_global_load_lds((const __attribute__((address_space(1))) unsigned int*)g,
                                   (__attribute__((address_space(3))) unsigned int*)lds_base,
                                   16, 0, 0);
}

// cheap exact-enough gelu: tanh form, err<~5e-4 abs (bf16 output)
__device__ inline float gelu_fast(float v) {
  float vc = fminf(fmaxf(v, -8.f), 8.f);
  float e = __expf(1.5957691216f * vc + 0.071354816f * vc * vc * vc);
  return v * e * __builtin_amdgcn_rcpf(e + 1.f);
}

// ---------------- f32 -> bf16 convert (weights) ----------------
__global__ void k_f2bf(const float* __restrict__ in, unsigned short* __restrict__ out, int n) {
  int i = blockIdx.x * blockDim.x + threadIdx.x;
  int stride = gridDim.x * blockDim.x;
  for (; i < n; i += stride) out[i] = f2bf(in[i]);
}

// ---------------- pack mask into transposed bitfield: maskT[bp][row][lr] bit f = mask[bp][row][f*16+lr]>0
__global__ void k_pack_mask(const int* __restrict__ mask, unsigned short* __restrict__ mt) {
  int idx = blockIdx.x * 256 + threadIdx.x;  // 128*256*16 = 524288
  int lr = idx & 15;
  int row = (idx >> 4) & 255;
  int bp = idx >> 12;
  const int* mp = mask + ((size_t)bp * NN + row) * NN;
  unsigned v = 0;
#pragma unroll
  for (int f = 0; f < 16; ++f) v |= (unsigned)(mp[f * 16 + lr] > 0) << f;
  mt[idx] = (unsigned short)v;
}

// ---------------- pack pos transposed bf16: posT[((h*256+row)*16+lr)*16+f] = pos[h][row][f*16+lr]
__global__ void k_pack_pos(const float* __restrict__ pos, unsigned short* __restrict__ pt) {
  int idx = blockIdx.x * 256 + threadIdx.x;  // 8*256*256 = 524288
  int f = idx & 15;
  int lr = (idx >> 4) & 15;
  int row = (idx >> 8) & 255;
  int h = idx >> 16;
  pt[idx] = f2bf(pos[((size_t)h * NN + row) * NN + f * 16 + lr]);
}

// ---------------- group norm over N (tokens), per (bp, c) ----------------
__global__ void k_gn(const float* __restrict__ x, const float* __restrict__ w,
                     const float* __restrict__ b, unsigned short* __restrict__ out) {
  int bp = blockIdx.x >> 1;
  int c = ((blockIdx.x & 1) << 8) + threadIdx.x;
  const float* xp = x + (size_t)bp * NN * CC + c;
  float s = 0.f, sq = 0.f;
  for (int n = 0; n < NN; ++n) { float v = xp[(size_t)n * CC]; s += v; sq += v * v; }
  float mean = s * (1.f / NN);
  float var = sq * (1.f / NN) - mean * mean;
  float rstd = rsqrtf(var + EPS);
  float ww = w[c], bb = b[c];
  unsigned short* op = out + (size_t)bp * NN * CC + c;
  for (int n = 0; n < NN; ++n) {
    float v = xp[(size_t)n * CC];
    op[(size_t)n * CC] = f2bf((v - mean) * rstd * ww + bb);
  }
}

// ---------------- bf16 MFMA GEMM: gload_lds + XOR swizzle, single-buffer, XCD-chunk swizzle ----
// C = A @ B^T + bias. A[M][K], Bw[Nn][K] row-major bf16. ALL epilogues use the swapped-operand
// layout: lane holds one output row m and 4 consecutive cols (n0c..n0c+3).
// EPI 1: out bf16 = gelu(v + bias)
// EPI 2: out f32  = resid + v + bias
// EPI 3: qkv split-store: Q(*0.125) -> qb[bh][m][d] (short4), K -> kb (short4),
//        V -> vtb[bh][d][m] (4x 2B, lanes write consecutive m -> coalesced)
template <int EPI>
__global__ __launch_bounds__(256) void k_gemm(const unsigned short* __restrict__ A,
                                              const unsigned short* __restrict__ Bw,
                                              const float* __restrict__ bias,
                                              const float* __restrict__ resid,
                                              unsigned short* __restrict__ outb,
                                              float* __restrict__ outf,
                                              unsigned short* __restrict__ qb,
                                              unsigned short* __restrict__ kb,
                                              unsigned short* __restrict__ vtb,
                                              int M, int Nn, int K) {
  constexpr int BM = 128, BN = 128, BK = 64;
  __shared__ unsigned short As[BM * BK];  // 16 KB, linear
  __shared__ unsigned short Bs[BN * BK];  // 16 KB, linear
  int tid = threadIdx.x;
  int lane = tid & 63, w = tid >> 6;
  int wm = w >> 1, wn = w & 1;
  // T1 XCD-chunk swizzle (all grids have nwg % 8 == 0)
  int nwgx = gridDim.x;
  int nwg = nwgx * gridDim.y;
  int linear = blockIdx.y * nwgx + blockIdx.x;
  int cpx = nwg >> 3;
  int swz = (linear & 7) * cpx + (linear >> 3);
  int bx = swz % nwgx, by = swz / nwgx;
  int m0 = by * BM, n0 = bx * BN;
  int rowc = lane >> 3;
  int csrc = (lane & 7) ^ (rowc & 7);
  int lr = lane & 15, lg = lane >> 4;
  f32x4_t acc[4][4] = {};
  for (int k0 = 0; k0 < K; k0 += BK) {
#pragma unroll
    for (int it = 0; it < 4; ++it) {
      int chunk = w * 4 + it;
      int grow = chunk * 8 + rowc;
      async_copy16(&As[chunk * 512], &A[(size_t)(m0 + grow) * K + k0 + csrc * 8]);
      async_copy16(&Bs[chunk * 512], &Bw[(size_t)(n0 + grow) * K + k0 + csrc * 8]);
    }
    __syncthreads();
#pragma unroll
    for (int kk = 0; kk < BK; kk += 32) {
      int kslot = (kk >> 3) + lg;
      short8_t af[4], bfr[4];
#pragma unroll
      for (int i = 0; i < 4; ++i) {
        int r = wm * 64 + i * 16 + lr;
        af[i] = *(const short8_t*)&As[r * 64 + ((kslot ^ (r & 7)) * 8)];
      }
#pragma unroll
      for (int j = 0; j < 4; ++j) {
        int r = wn * 64 + j * 16 + lr;
        bfr[j] = *(const short8_t*)&Bs[r * 64 + ((kslot ^ (r & 7)) * 8)];
      }
#pragma unroll
      for (int i = 0; i < 4; ++i)
#pragma unroll
        for (int j = 0; j < 4; ++j)
          acc[i][j] = __builtin_amdgcn_mfma_f32_16x16x32_bf16(bfr[j], af[i], acc[i][j], 0, 0, 0);
    }
    __syncthreads();
  }
  // swapped C-layout: lane holds row m, 4 consecutive cols
#pragma unroll
  for (int i = 0; i < 4; ++i) {
    int m = m0 + wm * 64 + i * 16 + lr;
#pragma unroll
    for (int j = 0; j < 4; ++j) {
      int n0c = n0 + wn * 64 + j * 16 + lg * 4;
      f32x4_t bv = *(const f32x4_t*)&bias[n0c];
      if (EPI == 1) {
        size_t off = (size_t)m * Nn + n0c;
        float g0 = gelu_fast(acc[i][j][0] + bv[0]);
        float g1 = gelu_fast(acc[i][j][1] + bv[1]);
        float g2 = gelu_fast(acc[i][j][2] + bv[2]);
        float g3 = gelu_fast(acc[i][j][3] + bv[3]);
        uint2_t pk;
        pk[0] = cvt_pk_bf16(g0, g1);
        pk[1] = cvt_pk_bf16(g2, g3);
        *(uint2_t*)&outb[off] = pk;
      } else if (EPI == 2) {
        size_t off = (size_t)m * Nn + n0c;
        f32x4_t rv = *(const f32x4_t*)&resid[off];
        f32x4_t o;
#pragma unroll
        for (int r2 = 0; r2 < 4; ++r2) o[r2] = rv[r2] + acc[i][j][r2] + bv[r2];
        *(f32x4_t*)&outf[off] = o;
      } else {  // EPI == 3: qkv split
        int which = n0c >> 9;          // 0=q 1=k 2=v (uniform across the 4 cols)
        int hh2 = (n0c >> 6) & 7;      // head
        int d0 = n0c & 63;             // 4 consecutive d
        int bp_ = m >> 8, mm = m & 255;
        size_t hb = (size_t)(bp_ * HH + hh2);
        if (which == 2) {
#pragma unroll
          for (int r2 = 0; r2 < 4; ++r2)
            vtb[(hb * HD + d0 + r2) * NN + mm] = f2bf(acc[i][j][r2] + bv[r2]);
        } else if (which == 0) {
          short4_t pk;
#pragma unroll
          for (int r2 = 0; r2 < 4; ++r2) pk[r2] = (short)f2bf((acc[i][j][r2] + bv[r2]) * 0.125f);
          *(short4_t*)&qb[(hb * NN + mm) * HD + d0] = pk;
        } else {
          short4_t pk;
#pragma unroll
          for (int r2 = 0; r2 < 4; ++r2) pk[r2] = (short)f2bf(acc[i][j][r2] + bv[r2]);
          *(short4_t*)&kb[(hb * NN + mm) * HD + d0] = pk;
        }
      }
    }
  }
}

// ---------------- fused attention v4: 2 q-chains per wave + XCD-pair swizzle -------
// grid: 2048 linear blocks; swizzled so the q-tile PAIR sharing (h,bp)'s K/V lands on ONE XCD.
__global__ __launch_bounds__(256, 2) void k_attn4(const unsigned short* __restrict__ qb,
                                                  const unsigned short* __restrict__ kb,
                                                  const unsigned short* __restrict__ vtb,
                                                  const unsigned short* __restrict__ maskT,
                                                  const unsigned short* __restrict__ posT,
                                                  unsigned short* __restrict__ attn_out) {
  constexpr int LMD = NN + 8;  // 264 elems; 2-way bank conflict (free)
  __shared__ unsigned short ps[128 * LMD];  // 66 KB
  int lin = blockIdx.x + (blockIdx.y << 1) + (blockIdx.z << 4);  // gridDim (2,8,128)
  int swz = (lin & 7) * 256 + (lin >> 3);   // pairs (2m,2m+1) <- lin, lin+8 -> same XCD
  int qt = swz & 1, h = (swz >> 1) & 7, bp = swz >> 4;
  int tid = threadIdx.x, lane = tid & 63, w = tid >> 6;
  int lr = lane & 15, lg = lane >> 4;
  int q0w = qt * 128 + w * 32;  // wave's first q row
  size_t bh = (size_t)(bp * HH + h);
  const unsigned short* Q = qb + bh * NN * HD;
  const unsigned short* K = kb + bh * NN * HD;
  const unsigned short* VT = vtb + bh * HD * NN;
  // Q fragments: 2 chains x 2 k-halves
  short8_t qf0[2], qf1[2];
#pragma unroll
  for (int c = 0; c < 2; ++c) {
    qf0[c] = *(const short8_t*)&Q[(size_t)(q0w + c * 16 + lr) * HD + lg * 8];
    qf1[c] = *(const short8_t*)&Q[(size_t)(q0w + c * 16 + lr) * HD + 32 + lg * 8];
  }
  // prefetch packed mask/pos for the wave's 8 rows (2 chains x 4)
  unsigned mbits[2][4];
  short8_t pv0[2][4], pv1[2][4];
#pragma unroll
  for (int c = 0; c < 2; ++c)
#pragma unroll
    for (int r2 = 0; r2 < 4; ++r2) {
      int qrow = q0w + c * 16 + lg * 4 + r2;
      mbits[c][r2] = maskT[((size_t)bp * NN + qrow) * 16 + lr];
      const unsigned short* pp = &posT[(((size_t)h * NN + qrow) * 16 + lr) * 16];
      pv0[c][r2] = *(const short8_t*)&pp[0];
      pv1[c][r2] = *(const short8_t*)&pp[8];
    }
  // QK^T: each K fragment pair feeds BOTH chains (load:MFMA = 1:2)
  f32x4_t sc[2][16] = {};
#pragma unroll
  for (int f = 0; f < 16; ++f) {
    short8_t b0 = *(const short8_t*)&K[(size_t)(f * 16 + lr) * HD + lg * 8];
    short8_t b1 = *(const short8_t*)&K[(size_t)(f * 16 + lr) * HD + 32 + lg * 8];
    sc[0][f] = __builtin_amdgcn_mfma_f32_16x16x32_bf16(qf0[0], b0, sc[0][f], 0, 0, 0);
    sc[1][f] = __builtin_amdgcn_mfma_f32_16x16x32_bf16(qf0[1], b0, sc[1][f], 0, 0, 0);
    sc[0][f] = __builtin_amdgcn_mfma_f32_16x16x32_bf16(qf1[0], b1, sc[0][f], 0, 0, 0);
    sc[1][f] = __builtin_amdgcn_mfma_f32_16x16x32_bf16(qf1[1], b1, sc[1][f], 0, 0, 0);
  }
  // mask + pos + softmax (scale pre-folded into Q)
#pragma unroll
  for (int c = 0; c < 2; ++c)
#pragma unroll
    for (int r2 = 0; r2 < 4; ++r2) {
      float mx = -3.0e38f;
#pragma unroll
      for (int f = 0; f < 16; ++f) {
        float pw = bf2f((unsigned short)((f < 8) ? pv0[c][r2][f] : pv1[c][r2][f - 8]));
        float s = ((mbits[c][r2] >> f) & 1) ? (sc[c][f][r2] + pw) : -1.0e9f;
        sc[c][f][r2] = s;
        mx = fmaxf(mx, s);
      }
      for (int d2 = 1; d2 < 16; d2 <<= 1) mx = fmaxf(mx, __shfl_xor(mx, d2));
      float sum = 0.f;
#pragma unroll
      for (int f = 0; f < 16; ++f) { float e = __expf(sc[c][f][r2] - mx); sc[c][f][r2] = e; sum += e; }
      for (int d2 = 1; d2 < 16; d2 <<= 1) sum += __shfl_xor(sum, d2);
      float inv = 1.f / sum;
      int prow = w * 32 + c * 16 + lg * 4 + r2;
#pragma unroll
      for (int f = 0; f < 16; ++f) ps[prow * LMD + f * 16 + lr] = f2bf(sc[c][f][r2] * inv);
    }
  // PV: each VT fragment feeds both chains; P rows wave-private (no block barrier)
  f32x4_t ao[2][4] = {};
#pragma unroll
  for (int kt = 0; kt < 8; ++kt) {
    short8_t a0 = *(const short8_t*)&ps[(w * 32 + lr) * LMD + kt * 32 + lg * 8];
    short8_t a1 = *(const short8_t*)&ps[(w * 32 + 16 + lr) * LMD + kt * 32 + lg * 8];
#pragma unroll
    for (int f = 0; f < 4; ++f) {
      short8_t b = *(const short8_t*)&VT[(size_t)(f * 16 + lr) * NN + kt * 32 + lg * 8];
      ao[0][f] = __builtin_amdgcn_mfma_f32_16x16x32_bf16(a0, b, ao[0][f], 0, 0, 0);
      ao[1][f] = __builtin_amdgcn_mfma_f32_16x16x32_bf16(a1, b, ao[1][f], 0, 0, 0);
    }
  }
#pragma unroll
  for (int c = 0; c < 2; ++c)
#pragma unroll
    for (int f = 0; f < 4; ++f)
#pragma unroll
      for (int r2 = 0; r2 < 4; ++r2) {
        int token = bp * NN + q0w + c * 16 + lg * 4 + r2;
        int d = f * 16 + lr;
        attn_out[(size_t)token * CC + h * HD + d] = f2bf(ao[c][f][r2]);
      }
}

extern "C" void kernel_launch(void* const* d_in, const int* in_sizes, int n_in,
                              void* d_out, int out_size, void* d_ws, size_t ws_size,
                              hipStream_t stream) {
  const float* x      = (const float*)d_in[0];
  const int*   mask   = (const int*)d_in[1];
  const float* pos    = (const float*)d_in[2];
  const float* n1w    = (const float*)d_in[3];
  const float* n1b    = (const float*)d_in[4];
  const float* qkv_w  = (const float*)d_in[5];
  const float* qkv_b  = (const float*)d_in[6];
  const float* proj_w = (const float*)d_in[7];
  const float* proj_b = (const float*)d_in[8];
  const float* n2w    = (const float*)d_in[9];
  const float* n2b    = (const float*)d_in[10];
  const float* w1     = (const float*)d_in[11];
  const float* b1     = (const float*)d_in[12];
  const float* w2     = (const float*)d_in[13];
  const float* b2     = (const float*)d_in[14];
  float* out = (float*)d_out;
  char* ws = (char*)d_ws;

  size_t off = 0;
  auto alloc = [&](size_t bytes) { size_t o = off; off += (bytes + 255) & ~(size_t)255; return o; };
  unsigned short* wqkv  = (unsigned short*)(ws + alloc((size_t)3 * CC * CC * 2));
  unsigned short* wproj = (unsigned short*)(ws + alloc((size_t)CC * CC * 2));
  unsigned short* wm1   = (unsigned short*)(ws + alloc((size_t)MLPD * CC * 2));
  unsigned short* wm2   = (unsigned short*)(ws + alloc((size_t)CC * MLPD * 2));
  unsigned short* maskT = (unsigned short*)(ws + alloc((size_t)BP * NN * 16 * 2));     // 1 MB
  unsigned short* posT  = (unsigned short*)(ws + alloc((size_t)HH * NN * NN * 2));     // 1 MB
  unsigned short* xn    = (unsigned short*)(ws + alloc((size_t)MTOT * CC * 2));   // 32 MB
  float*          x1    = (float*)(ws + alloc((size_t)MTOT * CC * 4));            // 64 MB
  size_t region = alloc((size_t)MTOT * MLPD * 2);                                 // 128 MB shared region
  const size_t BUFE = (size_t)MTOT * CC;  // elems per 32MB buffer
  unsigned short* qbuf  = (unsigned short*)(ws + region);
  unsigned short* kbuf  = qbuf + BUFE;
  unsigned short* vtbuf = qbuf + 2 * BUFE;
  unsigned short* attnb = qbuf + 3 * BUFE;
  unsigned short* hbuf  = (unsigned short*)(ws + region);  // reuses all 4 (dead by MLP time)

  // weight conversions + packs
  k_f2bf<<<1024, 256, 0, stream>>>(qkv_w, wqkv, 3 * CC * CC);
  k_f2bf<<<1024, 256, 0, stream>>>(proj_w, wproj, CC * CC);
  k_f2bf<<<1024, 256, 0, stream>>>(w1, wm1, MLPD * CC);
  k_f2bf<<<1024, 256, 0, stream>>>(w2, wm2, CC * MLPD);
  k_pack_mask<<<2048, 256, 0, stream>>>(mask, maskT);
  k_pack_pos<<<2048, 256, 0, stream>>>(pos, posT);

  // norm1
  k_gn<<<BP * 2, 256, 0, stream>>>(x, n1w, n1b, xn);
  // qkv = xn @ qkv_w^T + b, split-stored into q(*scale)/k/v^T head-major buffers
  k_gemm<3><<<dim3(3 * CC / 128, MTOT / 128), 256, 0, stream>>>(xn, wqkv, qkv_b, nullptr, nullptr, nullptr, qbuf, kbuf, vtbuf, MTOT, 3 * CC, CC);
  // attention
  k_attn4<<<dim3(2, HH, BP), 256, 0, stream>>>(qbuf, kbuf, vtbuf, maskT, posT, attnb);
  // x1 = x + attn @ proj_w^T + proj_b
  k_gemm<2><<<dim3(CC / 128, MTOT / 128), 256, 0, stream>>>(attnb, wproj, proj_b, x, nullptr, x1, nullptr, nullptr, nullptr, MTOT, CC, CC);
  // norm2
  k_gn<<<BP * 2, 256, 0, stream>>>(x1, n2w, n2b, xn);
  // h = gelu(xn @ w1^T + b1)
  k_gemm<1><<<dim3(MLPD / 128, MTOT / 128), 256, 0, stream>>>(xn, wm1, b1, nullptr, hbuf, nullptr, nullptr, nullptr, nullptr, MTOT, MLPD, CC);
  // out = x1 + h @ w2^T + b2
  k_gemm<2><<<dim3(CC / 128, MTOT / 128), 256, 0, stream>>>(hbuf, wm2, b2, x1, nullptr, out, nullptr, nullptr, nullptr, MTOT, CC, MLPD);
}

// Round 15
// 495.153 us; speedup vs baseline: 1.0579x; 1.0579x over previous
//
#include <hip/hip_runtime.h>
#include <hip/hip_bf16.h>

// Problem constants
constexpr int BB = 2, PP = 64, NN = 256, CC = 512, HH = 8, HD = 64, MLPD = 2048;
constexpr int BP = BB * PP;       // 128
constexpr int MTOT = BP * NN;     // 32768
constexpr float EPS = 1e-5f;

typedef __attribute__((ext_vector_type(8))) short short8_t;
typedef __attribute__((ext_vector_type(4))) short short4_t;
typedef __attribute__((ext_vector_type(4))) float f32x4_t;
typedef __attribute__((ext_vector_type(2))) unsigned int uint2_t;

__device__ inline unsigned short f2bf(float f) {
  union { float f; unsigned u; } v; v.f = f;
  unsigned r = v.u + 0x7fffu + ((v.u >> 16) & 1u);
  return (unsigned short)(r >> 16);
}
__device__ inline float bf2f(unsigned short u) {
  union { unsigned u; float f; } v; v.u = ((unsigned)u) << 16;
  return v.f;
}
// pack 2 f32 -> 2 bf16 in one dword (RNE), gfx950 HW op
__device__ inline unsigned int cvt_pk_bf16(float lo, float hi) {
  unsigned int r;
  asm("v_cvt_pk_bf16_f32 %0, %1, %2" : "=v"(r) : "v"(lo), "v"(hi));
  return r;
}

// async 16B global -> LDS (wave-uniform LDS base, per-lane global addr; HW writes base + lane*16)
__device__ inline void async_copy16(unsigned short* lds_base, const unsigned short* g) {
  __builtin_amdgcn_global_load_lds((const __attribute__((address_space(1))) unsigned int*)g,
                                   (__attribute__((address_space(3))) unsigned int*)lds_base,
                                   16, 0, 0);
}

// cheap exact-enough gelu: tanh form, err<~5e-4 abs (bf16 output)
__device__ inline float gelu_fast(float v) {
  float vc = fminf(fmaxf(v, -8.f), 8.f);
  float e = __expf(1.5957691216f * vc + 0.071354816f * vc * vc * vc);
  return v * e * __builtin_amdgcn_rcpf(e + 1.f);
}

// ---------------- f32 -> bf16 convert (weights) ----------------
__global__ void k_f2bf(const float* __restrict__ in, unsigned short* __restrict__ out, int n) {
  int i = blockIdx.x * blockDim.x + threadIdx.x;
  int stride = gridDim.x * blockDim.x;
  for (; i < n; i += stride) out[i] = f2bf(in[i]);
}

// ---------------- pack mask into transposed bitfield: maskT[bp][row][lr] bit f = mask[bp][row][f*16+lr]>0
__global__ void k_pack_mask(const int* __restrict__ mask, unsigned short* __restrict__ mt) {
  int idx = blockIdx.x * 256 + threadIdx.x;  // 128*256*16 = 524288
  int lr = idx & 15;
  int row = (idx >> 4) & 255;
  int bp = idx >> 12;
  const int* mp = mask + ((size_t)bp * NN + row) * NN;
  unsigned v = 0;
#pragma unroll
  for (int f = 0; f < 16; ++f) v |= (unsigned)(mp[f * 16 + lr] > 0) << f;
  mt[idx] = (unsigned short)v;
}

// ---------------- pack pos transposed bf16: posT[((h*256+row)*16+lr)*16+f] = pos[h][row][f*16+lr]
__global__ void k_pack_pos(const float* __restrict__ pos, unsigned short* __restrict__ pt) {
  int idx = blockIdx.x * 256 + threadIdx.x;  // 8*256*256 = 524288
  int f = idx & 15;
  int lr = (idx >> 4) & 15;
  int row = (idx >> 8) & 255;
  int h = idx >> 16;
  pt[idx] = f2bf(pos[((size_t)h * NN + row) * NN + f * 16 + lr]);
}

// ---------------- group norm over N (tokens), per (bp, c); IN=0 f32 input, IN=1 bf16 input ----
template <int IN>
__global__ void k_gn(const void* __restrict__ xin, const float* __restrict__ w,
                     const float* __restrict__ b, unsigned short* __restrict__ out) {
  int bp = blockIdx.x >> 1;
  int c = ((blockIdx.x & 1) << 8) + threadIdx.x;
  float s = 0.f, sq = 0.f;
  const float* xf = (const float*)xin + (size_t)bp * NN * CC + c;
  const unsigned short* xb = (const unsigned short*)xin + (size_t)bp * NN * CC + c;
  for (int n = 0; n < NN; ++n) {
    float v = (IN == 0) ? xf[(size_t)n * CC] : bf2f(xb[(size_t)n * CC]);
    s += v; sq += v * v;
  }
  float mean = s * (1.f / NN);
  float var = sq * (1.f / NN) - mean * mean;
  float rstd = rsqrtf(var + EPS);
  float ww = w[c], bb = b[c];
  unsigned short* op = out + (size_t)bp * NN * CC + c;
  for (int n = 0; n < NN; ++n) {
    float v = (IN == 0) ? xf[(size_t)n * CC] : bf2f(xb[(size_t)n * CC]);
    op[(size_t)n * CC] = f2bf((v - mean) * rstd * ww + bb);
  }
}

// ---------------- bf16 MFMA GEMM: gload_lds + XOR swizzle, single-buffer, XCD-chunk swizzle ----
// C = A @ B^T + bias. A[M][K], Bw[Nn][K] row-major bf16.
// EPI 1/2/5 use SWAPPED mfma operands (lane holds row m, 4 consecutive cols):
//   EPI 1: bf16 out = gelu(v + bias)            [mlp-up]
//   EPI 2: bf16 out = f32 resid + v + bias      [proj: x1 = x + attn]
//   EPI 5: f32 out  = bf16 resid + v + bias     [mlp-down: out = x1 + mlp]
// EPI 3 qkv split-store (unswapped): Q(*0.125) -> qb, K -> kb, V -> vtb[bp*H+h][d][m]
template <int EPI>
__global__ __launch_bounds__(256) void k_gemm(const unsigned short* __restrict__ A,
                                              const unsigned short* __restrict__ Bw,
                                              const float* __restrict__ bias,
                                              const float* __restrict__ resid,
                                              const unsigned short* __restrict__ residb,
                                              unsigned short* __restrict__ outb,
                                              float* __restrict__ outf,
                                              unsigned short* __restrict__ qb,
                                              unsigned short* __restrict__ kb,
                                              unsigned short* __restrict__ vtb,
                                              int M, int Nn, int K) {
  constexpr bool SW = (EPI != 3);
  constexpr int BM = 128, BN = 128, BK = 64;
  __shared__ unsigned short As[BM * BK];  // 16 KB, linear
  __shared__ unsigned short Bs[BN * BK];  // 16 KB, linear
  int tid = threadIdx.x;
  int lane = tid & 63, w = tid >> 6;
  int wm = w >> 1, wn = w & 1;
  // T1 XCD-chunk swizzle (all grids have nwg % 8 == 0)
  int nwgx = gridDim.x;
  int nwg = nwgx * gridDim.y;
  int linear = blockIdx.y * nwgx + blockIdx.x;
  int cpx = nwg >> 3;
  int swz = (linear & 7) * cpx + (linear >> 3);
  int bx = swz % nwgx, by = swz / nwgx;
  int m0 = by * BM, n0 = bx * BN;
  int rowc = lane >> 3;
  int csrc = (lane & 7) ^ (rowc & 7);
  int lr = lane & 15, lg = lane >> 4;
  f32x4_t acc[4][4] = {};
  for (int k0 = 0; k0 < K; k0 += BK) {
#pragma unroll
    for (int it = 0; it < 4; ++it) {
      int chunk = w * 4 + it;
      int grow = chunk * 8 + rowc;
      async_copy16(&As[chunk * 512], &A[(size_t)(m0 + grow) * K + k0 + csrc * 8]);
      async_copy16(&Bs[chunk * 512], &Bw[(size_t)(n0 + grow) * K + k0 + csrc * 8]);
    }
    __syncthreads();
#pragma unroll
    for (int kk = 0; kk < BK; kk += 32) {
      int kslot = (kk >> 3) + lg;
      short8_t af[4], bfr[4];
#pragma unroll
      for (int i = 0; i < 4; ++i) {
        int r = wm * 64 + i * 16 + lr;
        af[i] = *(const short8_t*)&As[r * 64 + ((kslot ^ (r & 7)) * 8)];
      }
#pragma unroll
      for (int j = 0; j < 4; ++j) {
        int r = wn * 64 + j * 16 + lr;
        bfr[j] = *(const short8_t*)&Bs[r * 64 + ((kslot ^ (r & 7)) * 8)];
      }
#pragma unroll
      for (int i = 0; i < 4; ++i)
#pragma unroll
        for (int j = 0; j < 4; ++j) {
          if (SW)
            acc[i][j] = __builtin_amdgcn_mfma_f32_16x16x32_bf16(bfr[j], af[i], acc[i][j], 0, 0, 0);
          else
            acc[i][j] = __builtin_amdgcn_mfma_f32_16x16x32_bf16(af[i], bfr[j], acc[i][j], 0, 0, 0);
        }
    }
    __syncthreads();
  }
  if (SW) {
    // lane holds row m = m0+wm*64+i*16+lr, cols n0c..n0c+3 with n0c = n0+wn*64+j*16+lg*4
#pragma unroll
    for (int i = 0; i < 4; ++i) {
      int m = m0 + wm * 64 + i * 16 + lr;
#pragma unroll
      for (int j = 0; j < 4; ++j) {
        int n0c = n0 + wn * 64 + j * 16 + lg * 4;
        f32x4_t bv = *(const f32x4_t*)&bias[n0c];
        size_t off = (size_t)m * Nn + n0c;
        if (EPI == 1) {
          float g0 = gelu_fast(acc[i][j][0] + bv[0]);
          float g1 = gelu_fast(acc[i][j][1] + bv[1]);
          float g2 = gelu_fast(acc[i][j][2] + bv[2]);
          float g3 = gelu_fast(acc[i][j][3] + bv[3]);
          uint2_t pk;
          pk[0] = cvt_pk_bf16(g0, g1);
          pk[1] = cvt_pk_bf16(g2, g3);
          *(uint2_t*)&outb[off] = pk;
        } else if (EPI == 2) {
          f32x4_t rv = *(const f32x4_t*)&resid[off];
          uint2_t pk;
          pk[0] = cvt_pk_bf16(rv[0] + acc[i][j][0] + bv[0], rv[1] + acc[i][j][1] + bv[1]);
          pk[1] = cvt_pk_bf16(rv[2] + acc[i][j][2] + bv[2], rv[3] + acc[i][j][3] + bv[3]);
          *(uint2_t*)&outb[off] = pk;
        } else {  // EPI == 5
          short4_t rv = *(const short4_t*)&residb[off];
          f32x4_t o;
#pragma unroll
          for (int r2 = 0; r2 < 4; ++r2)
            o[r2] = bf2f((unsigned short)rv[r2]) + acc[i][j][r2] + bv[r2];
          *(f32x4_t*)&outf[off] = o;
        }
      }
    }
  } else {
    // EPI == 3, unswapped: lane holds col = ...+lr, rows row0..row0+3
#pragma unroll
    for (int i = 0; i < 4; ++i)
#pragma unroll
      for (int j = 0; j < 4; ++j) {
        int col = n0 + wn * 64 + j * 16 + lr;
        float bv = bias[col];
        int row0 = m0 + wm * 64 + i * 16 + lg * 4;
        int which = col >> 9;         // 0=q 1=k 2=v (wave-uniform)
        int hh2 = (col >> 6) & 7;     // head (wave-uniform)
        int d = col & 63;
        int bp_ = row0 >> 8, m = row0 & 255;
        size_t hb = (size_t)(bp_ * HH + hh2);
        if (which == 2) {
          short4_t pk;
#pragma unroll
          for (int r2 = 0; r2 < 4; ++r2) pk[r2] = (short)f2bf(acc[i][j][r2] + bv);
          *(short4_t*)&vtb[(hb * HD + d) * NN + m] = pk;
        } else if (which == 0) {
#pragma unroll
          for (int r2 = 0; r2 < 4; ++r2)
            qb[(hb * NN + m + r2) * HD + d] = f2bf((acc[i][j][r2] + bv) * 0.125f);
        } else {
#pragma unroll
          for (int r2 = 0; r2 < 4; ++r2)
            kb[(hb * NN + m + r2) * HD + d] = f2bf(acc[i][j][r2] + bv);
        }
      }
  }
}

// ---------------- fused attention v4: 2 q-chains per wave (K/V fragment reuse) -------
// grid: (2, H, BP); 256 threads = 4 waves; wave owns 32 q-rows = 2 independent 16-row chains.
__global__ __launch_bounds__(256, 2) void k_attn4(const unsigned short* __restrict__ qb,
                                                  const unsigned short* __restrict__ kb,
                                                  const unsigned short* __restrict__ vtb,
                                                  const unsigned short* __restrict__ maskT,
                                                  const unsigned short* __restrict__ posT,
                                                  unsigned short* __restrict__ attn_out) {
  constexpr int LMD = NN + 8;  // 264 elems; 2-way bank conflict (free)
  __shared__ unsigned short ps[128 * LMD];  // 66 KB
  int qt = blockIdx.x, h = blockIdx.y, bp = blockIdx.z;
  int tid = threadIdx.x, lane = tid & 63, w = tid >> 6;
  int lr = lane & 15, lg = lane >> 4;
  int q0w = qt * 128 + w * 32;  // wave's first q row
  size_t bh = (size_t)(bp * HH + h);
  const unsigned short* Q = qb + bh * NN * HD;
  const unsigned short* K = kb + bh * NN * HD;
  const unsigned short* VT = vtb + bh * HD * NN;
  // Q fragments: 2 chains x 2 k-halves
  short8_t qf0[2], qf1[2];
#pragma unroll
  for (int c = 0; c < 2; ++c) {
    qf0[c] = *(const short8_t*)&Q[(size_t)(q0w + c * 16 + lr) * HD + lg * 8];
    qf1[c] = *(const short8_t*)&Q[(size_t)(q0w + c * 16 + lr) * HD + 32 + lg * 8];
  }
  // prefetch packed mask/pos for the wave's 8 rows (2 chains x 4)
  unsigned mbits[2][4];
  short8_t pv0[2][4], pv1[2][4];
#pragma unroll
  for (int c = 0; c < 2; ++c)
#pragma unroll
    for (int r2 = 0; r2 < 4; ++r2) {
      int qrow = q0w + c * 16 + lg * 4 + r2;
      mbits[c][r2] = maskT[((size_t)bp * NN + qrow) * 16 + lr];
      const unsigned short* pp = &posT[(((size_t)h * NN + qrow) * 16 + lr) * 16];
      pv0[c][r2] = *(const short8_t*)&pp[0];
      pv1[c][r2] = *(const short8_t*)&pp[8];
    }
  // QK^T: each K fragment pair feeds BOTH chains (load:MFMA = 1:2)
  f32x4_t sc[2][16] = {};
#pragma unroll
  for (int f = 0; f < 16; ++f) {
    short8_t b0 = *(const short8_t*)&K[(size_t)(f * 16 + lr) * HD + lg * 8];
    short8_t b1 = *(const short8_t*)&K[(size_t)(f * 16 + lr) * HD + 32 + lg * 8];
    sc[0][f] = __builtin_amdgcn_mfma_f32_16x16x32_bf16(qf0[0], b0, sc[0][f], 0, 0, 0);
    sc[1][f] = __builtin_amdgcn_mfma_f32_16x16x32_bf16(qf0[1], b0, sc[1][f], 0, 0, 0);
    sc[0][f] = __builtin_amdgcn_mfma_f32_16x16x32_bf16(qf1[0], b1, sc[0][f], 0, 0, 0);
    sc[1][f] = __builtin_amdgcn_mfma_f32_16x16x32_bf16(qf1[1], b1, sc[1][f], 0, 0, 0);
  }
  // mask + pos + softmax (scale pre-folded into Q)
#pragma unroll
  for (int c = 0; c < 2; ++c)
#pragma unroll
    for (int r2 = 0; r2 < 4; ++r2) {
      float mx = -3.0e38f;
#pragma unroll
      for (int f = 0; f < 16; ++f) {
        float pw = bf2f((unsigned short)((f < 8) ? pv0[c][r2][f] : pv1[c][r2][f - 8]));
        float s = ((mbits[c][r2] >> f) & 1) ? (sc[c][f][r2] + pw) : -1.0e9f;
        sc[c][f][r2] = s;
        mx = fmaxf(mx, s);
      }
      for (int d2 = 1; d2 < 16; d2 <<= 1) mx = fmaxf(mx, __shfl_xor(mx, d2));
      float sum = 0.f;
#pragma unroll
      for (int f = 0; f < 16; ++f) { float e = __expf(sc[c][f][r2] - mx); sc[c][f][r2] = e; sum += e; }
      for (int d2 = 1; d2 < 16; d2 <<= 1) sum += __shfl_xor(sum, d2);
      float inv = 1.f / sum;
      int prow = w * 32 + c * 16 + lg * 4 + r2;
#pragma unroll
      for (int f = 0; f < 16; ++f) ps[prow * LMD + f * 16 + lr] = f2bf(sc[c][f][r2] * inv);
    }
  // PV: each VT fragment feeds both chains; P rows wave-private (no block barrier)
  f32x4_t ao[2][4] = {};
#pragma unroll
  for (int kt = 0; kt < 8; ++kt) {
    short8_t a0 = *(const short8_t*)&ps[(w * 32 + lr) * LMD + kt * 32 + lg * 8];
    short8_t a1 = *(const short8_t*)&ps[(w * 32 + 16 + lr) * LMD + kt * 32 + lg * 8];
#pragma unroll
    for (int f = 0; f < 4; ++f) {
      short8_t b = *(const short8_t*)&VT[(size_t)(f * 16 + lr) * NN + kt * 32 + lg * 8];
      ao[0][f] = __builtin_amdgcn_mfma_f32_16x16x32_bf16(a0, b, ao[0][f], 0, 0, 0);
      ao[1][f] = __builtin_amdgcn_mfma_f32_16x16x32_bf16(a1, b, ao[1][f], 0, 0, 0);
    }
  }
#pragma unroll
  for (int c = 0; c < 2; ++c)
#pragma unroll
    for (int f = 0; f < 4; ++f)
#pragma unroll
      for (int r2 = 0; r2 < 4; ++r2) {
        int token = bp * NN + q0w + c * 16 + lg * 4 + r2;
        int d = f * 16 + lr;
        attn_out[(size_t)token * CC + h * HD + d] = f2bf(ao[c][f][r2]);
      }
}

extern "C" void kernel_launch(void* const* d_in, const int* in_sizes, int n_in,
                              void* d_out, int out_size, void* d_ws, size_t ws_size,
                              hipStream_t stream) {
  const float* x      = (const float*)d_in[0];
  const int*   mask   = (const int*)d_in[1];
  const float* pos    = (const float*)d_in[2];
  const float* n1w    = (const float*)d_in[3];
  const float* n1b    = (const float*)d_in[4];
  const float* qkv_w  = (const float*)d_in[5];
  const float* qkv_b  = (const float*)d_in[6];
  const float* proj_w = (const float*)d_in[7];
  const float* proj_b = (const float*)d_in[8];
  const float* n2w    = (const float*)d_in[9];
  const float* n2b    = (const float*)d_in[10];
  const float* w1     = (const float*)d_in[11];
  const float* b1     = (const float*)d_in[12];
  const float* w2     = (const float*)d_in[13];
  const float* b2     = (const float*)d_in[14];
  float* out = (float*)d_out;
  char* ws = (char*)d_ws;

  size_t off = 0;
  auto alloc = [&](size_t bytes) { size_t o = off; off += (bytes + 255) & ~(size_t)255; return o; };
  unsigned short* wqkv  = (unsigned short*)(ws + alloc((size_t)3 * CC * CC * 2));
  unsigned short* wproj = (unsigned short*)(ws + alloc((size_t)CC * CC * 2));
  unsigned short* wm1   = (unsigned short*)(ws + alloc((size_t)MLPD * CC * 2));
  unsigned short* wm2   = (unsigned short*)(ws + alloc((size_t)CC * MLPD * 2));
  unsigned short* maskT = (unsigned short*)(ws + alloc((size_t)BP * NN * 16 * 2));     // 1 MB
  unsigned short* posT  = (unsigned short*)(ws + alloc((size_t)HH * NN * NN * 2));     // 1 MB
  unsigned short* xn    = (unsigned short*)(ws + alloc((size_t)MTOT * CC * 2));   // 32 MB
  unsigned short* x1b   = (unsigned short*)(ws + alloc((size_t)MTOT * CC * 2));   // 32 MB bf16 residual
  size_t region = alloc((size_t)MTOT * MLPD * 2);                                 // 128 MB shared region
  const size_t BUFE = (size_t)MTOT * CC;  // elems per 32MB buffer
  unsigned short* qbuf  = (unsigned short*)(ws + region);
  unsigned short* kbuf  = qbuf + BUFE;
  unsigned short* vtbuf = qbuf + 2 * BUFE;
  unsigned short* attnb = qbuf + 3 * BUFE;
  unsigned short* hbuf  = (unsigned short*)(ws + region);  // reuses all 4 (dead by MLP time)

  // weight conversions + packs
  k_f2bf<<<1024, 256, 0, stream>>>(qkv_w, wqkv, 3 * CC * CC);
  k_f2bf<<<1024, 256, 0, stream>>>(proj_w, wproj, CC * CC);
  k_f2bf<<<1024, 256, 0, stream>>>(w1, wm1, MLPD * CC);
  k_f2bf<<<1024, 256, 0, stream>>>(w2, wm2, CC * MLPD);
  k_pack_mask<<<2048, 256, 0, stream>>>(mask, maskT);
  k_pack_pos<<<2048, 256, 0, stream>>>(pos, posT);

  // norm1 (f32 input)
  k_gn<0><<<BP * 2, 256, 0, stream>>>(x, n1w, n1b, xn);
  // qkv = xn @ qkv_w^T + b, split-stored into q(*scale)/k/v^T head-major buffers
  k_gemm<3><<<dim3(3 * CC / 128, MTOT / 128), 256, 0, stream>>>(xn, wqkv, qkv_b, nullptr, nullptr, nullptr, nullptr, qbuf, kbuf, vtbuf, MTOT, 3 * CC, CC);
  // attention
  k_attn4<<<dim3(2, HH, BP), 256, 0, stream>>>(qbuf, kbuf, vtbuf, maskT, posT, attnb);
  // x1b = bf16(x + attn @ proj_w^T + proj_b)
  k_gemm<2><<<dim3(CC / 128, MTOT / 128), 256, 0, stream>>>(attnb, wproj, proj_b, x, nullptr, x1b, nullptr, nullptr, nullptr, nullptr, MTOT, CC, CC);
  // norm2 (bf16 input)
  k_gn<1><<<BP * 2, 256, 0, stream>>>(x1b, n2w, n2b, xn);
  // h = gelu(xn @ w1^T + b1)
  k_gemm<1><<<dim3(MLPD / 128, MTOT / 128), 256, 0, stream>>>(xn, wm1, b1, nullptr, nullptr, hbuf, nullptr, nullptr, nullptr, nullptr, MTOT, MLPD, CC);
  // out = x1b + h @ w2^T + b2  (f32 output)
  k_gemm<5><<<dim3(CC / 128, MTOT / 128), 256, 0, stream>>>(hbuf, wm2, b2, nullptr, x1b, nullptr, out, nullptr, nullptr, nullptr, MTOT, CC, MLPD);
}

// Round 17
// 480.122 us; speedup vs baseline: 1.0910x; 1.0313x over previous
//
#include <hip/hip_runtime.h>
#include <hip/hip_bf16.h>

// Problem constants
constexpr int BB = 2, PP = 64, NN = 256, CC = 512, HH = 8, HD = 64, MLPD = 2048;
constexpr int BP = BB * PP;       // 128
constexpr int MTOT = BP * NN;     // 32768
constexpr float EPS = 1e-5f;

typedef __attribute__((ext_vector_type(8))) short short8_t;
typedef __attribute__((ext_vector_type(4))) short short4_t;
typedef __attribute__((ext_vector_type(4))) float f32x4_t;
typedef __attribute__((ext_vector_type(2))) unsigned int uint2_t;

__device__ inline unsigned short f2bf(float f) {
  union { float f; unsigned u; } v; v.f = f;
  unsigned r = v.u + 0x7fffu + ((v.u >> 16) & 1u);
  return (unsigned short)(r >> 16);
}
__device__ inline float bf2f(unsigned short u) {
  union { unsigned u; float f; } v; v.u = ((unsigned)u) << 16;
  return v.f;
}
// pack 2 f32 -> 2 bf16 in one dword (RNE), gfx950 HW op
__device__ inline unsigned int cvt_pk_bf16(float lo, float hi) {
  unsigned int r;
  asm("v_cvt_pk_bf16_f32 %0, %1, %2" : "=v"(r) : "v"(lo), "v"(hi));
  return r;
}

// async 16B global -> LDS (wave-uniform LDS base, per-lane global addr; HW writes base + lane*16)
__device__ inline void async_copy16(unsigned short* lds_base, const unsigned short* g) {
  __builtin_amdgcn_global_load_lds((const __attribute__((address_space(1))) unsigned int*)g,
                                   (__attribute__((address_space(3))) unsigned int*)lds_base,
                                   16, 0, 0);
}

// cheap exact-enough gelu: tanh form, err<~5e-4 abs (bf16 output)
__device__ inline float gelu_fast(float v) {
  float vc = fminf(fmaxf(v, -8.f), 8.f);
  float e = __expf(1.5957691216f * vc + 0.071354816f * vc * vc * vc);
  return v * e * __builtin_amdgcn_rcpf(e + 1.f);
}

// ---------------- fused prologue: weight converts + mask/pos packs in ONE launch ----------------
constexpr int N_QKVW = 3 * CC * CC;          // 786432
constexpr int N_PROJW = CC * CC;             // 262144
constexpr int N_W1 = MLPD * CC;              // 1048576
constexpr int N_W2 = CC * MLPD;              // 1048576
constexpr int N_MASK = BP * NN * 16;         // 524288
constexpr int N_POS = HH * NN * NN;          // 524288
constexpr int C1 = N_QKVW;
constexpr int C2 = C1 + N_PROJW;
constexpr int C3 = C2 + N_W1;
constexpr int C4 = C3 + N_W2;
constexpr int C5 = C4 + N_MASK;
constexpr int C6 = C5 + N_POS;               // 4194304

__global__ void k_prep(const float* __restrict__ qkv_w, const float* __restrict__ proj_w,
                       const float* __restrict__ w1, const float* __restrict__ w2,
                       const int* __restrict__ mask, const float* __restrict__ pos,
                       unsigned short* __restrict__ wqkv, unsigned short* __restrict__ wproj,
                       unsigned short* __restrict__ wm1, unsigned short* __restrict__ wm2,
                       unsigned short* __restrict__ mt, unsigned short* __restrict__ pt) {
  int stride = gridDim.x * blockDim.x;
  for (int idx = blockIdx.x * blockDim.x + threadIdx.x; idx < C6; idx += stride) {
    if (idx < C1) {
      wqkv[idx] = f2bf(qkv_w[idx]);
    } else if (idx < C2) {
      int i = idx - C1; wproj[i] = f2bf(proj_w[i]);
    } else if (idx < C3) {
      int i = idx - C2; wm1[i] = f2bf(w1[i]);
    } else if (idx < C4) {
      int i = idx - C3; wm2[i] = f2bf(w2[i]);
    } else if (idx < C5) {
      int i = idx - C4;
      int lr = i & 15;
      int row = (i >> 4) & 255;
      int bp = i >> 12;
      const int* mp = mask + ((size_t)bp * NN + row) * NN;
      unsigned v = 0;
#pragma unroll
      for (int f = 0; f < 16; ++f) v |= (unsigned)(mp[f * 16 + lr] > 0) << f;
      mt[i] = (unsigned short)v;
    } else {
      int i = idx - C5;
      int f = i & 15;
      int lr = (i >> 4) & 15;
      int row = (i >> 8) & 255;
      int h = i >> 16;
      pt[i] = f2bf(pos[((size_t)h * NN + row) * NN + f * 16 + lr]);
    }
  }
}

// ---------------- group norm over N (tokens), per (bp, c); IN=0 f32 input, IN=1 bf16 input ----
template <int IN>
__global__ void k_gn(const void* __restrict__ xin, const float* __restrict__ w,
                     const float* __restrict__ b, unsigned short* __restrict__ out) {
  int bp = blockIdx.x >> 1;
  int c = ((blockIdx.x & 1) << 8) + threadIdx.x;
  float s = 0.f, sq = 0.f;
  const float* xf = (const float*)xin + (size_t)bp * NN * CC + c;
  const unsigned short* xb = (const unsigned short*)xin + (size_t)bp * NN * CC + c;
  for (int n = 0; n < NN; ++n) {
    float v = (IN == 0) ? xf[(size_t)n * CC] : bf2f(xb[(size_t)n * CC]);
    s += v; sq += v * v;
  }
  float mean = s * (1.f / NN);
  float var = sq * (1.f / NN) - mean * mean;
  float rstd = rsqrtf(var + EPS);
  float ww = w[c], bb = b[c];
  unsigned short* op = out + (size_t)bp * NN * CC + c;
  for (int n = 0; n < NN; ++n) {
    float v = (IN == 0) ? xf[(size_t)n * CC] : bf2f(xb[(size_t)n * CC]);
    op[(size_t)n * CC] = f2bf((v - mean) * rstd * ww + bb);
  }
}

// ---------------- bf16 MFMA GEMM: gload_lds + XOR swizzle, single-buffer, XCD-chunk swizzle ----
// C = A @ B^T + bias. A[M][K], Bw[Nn][K] row-major bf16.
// EPI 1/2/5 use SWAPPED mfma operands (lane holds row m, 4 consecutive cols):
//   EPI 1: bf16 out = gelu(v + bias)            [mlp-up]
//   EPI 2: bf16 out = f32 resid + v + bias      [proj: x1 = x + attn]
//   EPI 5: f32 out  = bf16 resid + v + bias     [mlp-down: out = x1 + mlp]
// EPI 3 qkv split-store (unswapped): Q(*0.125) -> qb, K -> kb, V -> vtb[bp*H+h][d][m]
template <int EPI>
__global__ __launch_bounds__(256) void k_gemm(const unsigned short* __restrict__ A,
                                              const unsigned short* __restrict__ Bw,
                                              const float* __restrict__ bias,
                                              const float* __restrict__ resid,
                                              const unsigned short* __restrict__ residb,
                                              unsigned short* __restrict__ outb,
                                              float* __restrict__ outf,
                                              unsigned short* __restrict__ qb,
                                              unsigned short* __restrict__ kb,
                                              unsigned short* __restrict__ vtb,
                                              int M, int Nn, int K) {
  constexpr bool SW = (EPI != 3);
  constexpr int BM = 128, BN = 128, BK = 64;
  __shared__ unsigned short As[BM * BK];  // 16 KB, linear
  __shared__ unsigned short Bs[BN * BK];  // 16 KB, linear
  int tid = threadIdx.x;
  int lane = tid & 63, w = tid >> 6;
  int wm = w >> 1, wn = w & 1;
  // T1 XCD-chunk swizzle (all grids have nwg % 8 == 0)
  int nwgx = gridDim.x;
  int nwg = nwgx * gridDim.y;
  int linear = blockIdx.y * nwgx + blockIdx.x;
  int cpx = nwg >> 3;
  int swz = (linear & 7) * cpx + (linear >> 3);
  int bx = swz % nwgx, by = swz / nwgx;
  int m0 = by * BM, n0 = bx * BN;
  int rowc = lane >> 3;
  int csrc = (lane & 7) ^ (rowc & 7);
  int lr = lane & 15, lg = lane >> 4;
  f32x4_t acc[4][4] = {};
  for (int k0 = 0; k0 < K; k0 += BK) {
#pragma unroll
    for (int it = 0; it < 4; ++it) {
      int chunk = w * 4 + it;
      int grow = chunk * 8 + rowc;
      async_copy16(&As[chunk * 512], &A[(size_t)(m0 + grow) * K + k0 + csrc * 8]);
      async_copy16(&Bs[chunk * 512], &Bw[(size_t)(n0 + grow) * K + k0 + csrc * 8]);
    }
    __syncthreads();
#pragma unroll
    for (int kk = 0; kk < BK; kk += 32) {
      int kslot = (kk >> 3) + lg;
      short8_t af[4], bfr[4];
#pragma unroll
      for (int i = 0; i < 4; ++i) {
        int r = wm * 64 + i * 16 + lr;
        af[i] = *(const short8_t*)&As[r * 64 + ((kslot ^ (r & 7)) * 8)];
      }
#pragma unroll
      for (int j = 0; j < 4; ++j) {
        int r = wn * 64 + j * 16 + lr;
        bfr[j] = *(const short8_t*)&Bs[r * 64 + ((kslot ^ (r & 7)) * 8)];
      }
#pragma unroll
      for (int i = 0; i < 4; ++i)
#pragma unroll
        for (int j = 0; j < 4; ++j) {
          if (SW)
            acc[i][j] = __builtin_amdgcn_mfma_f32_16x16x32_bf16(bfr[j], af[i], acc[i][j], 0, 0, 0);
          else
            acc[i][j] = __builtin_amdgcn_mfma_f32_16x16x32_bf16(af[i], bfr[j], acc[i][j], 0, 0, 0);
        }
    }
    __syncthreads();
  }
  if (SW) {
    // lane holds row m = m0+wm*64+i*16+lr, cols n0c..n0c+3 with n0c = n0+wn*64+j*16+lg*4
#pragma unroll
    for (int i = 0; i < 4; ++i) {
      int m = m0 + wm * 64 + i * 16 + lr;
#pragma unroll
      for (int j = 0; j < 4; ++j) {
        int n0c = n0 + wn * 64 + j * 16 + lg * 4;
        f32x4_t bv = *(const f32x4_t*)&bias[n0c];
        size_t off = (size_t)m * Nn + n0c;
        if (EPI == 1) {
          float g0 = gelu_fast(acc[i][j][0] + bv[0]);
          float g1 = gelu_fast(acc[i][j][1] + bv[1]);
          float g2 = gelu_fast(acc[i][j][2] + bv[2]);
          float g3 = gelu_fast(acc[i][j][3] + bv[3]);
          uint2_t pk;
          pk[0] = cvt_pk_bf16(g0, g1);
          pk[1] = cvt_pk_bf16(g2, g3);
          *(uint2_t*)&outb[off] = pk;
        } else if (EPI == 2) {
          f32x4_t rv = *(const f32x4_t*)&resid[off];
          uint2_t pk;
          pk[0] = cvt_pk_bf16(rv[0] + acc[i][j][0] + bv[0], rv[1] + acc[i][j][1] + bv[1]);
          pk[1] = cvt_pk_bf16(rv[2] + acc[i][j][2] + bv[2], rv[3] + acc[i][j][3] + bv[3]);
          *(uint2_t*)&outb[off] = pk;
        } else {  // EPI == 5
          short4_t rv = *(const short4_t*)&residb[off];
          f32x4_t o;
#pragma unroll
          for (int r2 = 0; r2 < 4; ++r2)
            o[r2] = bf2f((unsigned short)rv[r2]) + acc[i][j][r2] + bv[r2];
          *(f32x4_t*)&outf[off] = o;
        }
      }
    }
  } else {
    // EPI == 3, unswapped: lane holds col = ...+lr, rows row0..row0+3
#pragma unroll
    for (int i = 0; i < 4; ++i)
#pragma unroll
      for (int j = 0; j < 4; ++j) {
        int col = n0 + wn * 64 + j * 16 + lr;
        float bv = bias[col];
        int row0 = m0 + wm * 64 + i * 16 + lg * 4;
        int which = col >> 9;         // 0=q 1=k 2=v (wave-uniform)
        int hh2 = (col >> 6) & 7;     // head (wave-uniform)
        int d = col & 63;
        int bp_ = row0 >> 8, m = row0 & 255;
        size_t hb = (size_t)(bp_ * HH + hh2);
        if (which == 2) {
          short4_t pk;
#pragma unroll
          for (int r2 = 0; r2 < 4; ++r2) pk[r2] = (short)f2bf(acc[i][j][r2] + bv);
          *(short4_t*)&vtb[(hb * HD + d) * NN + m] = pk;
        } else if (which == 0) {
#pragma unroll
          for (int r2 = 0; r2 < 4; ++r2)
            qb[(hb * NN + m + r2) * HD + d] = f2bf((acc[i][j][r2] + bv) * 0.125f);
        } else {
#pragma unroll
          for (int r2 = 0; r2 < 4; ++r2)
            kb[(hb * NN + m + r2) * HD + d] = f2bf(acc[i][j][r2] + bv);
        }
      }
  }
}

// ---------------- fused attention v4: 2 q-chains per wave (K/V fragment reuse) -------
// grid: (2, H, BP); 256 threads = 4 waves; wave owns 32 q-rows = 2 independent 16-row chains.
__global__ __launch_bounds__(256, 2) void k_attn4(const unsigned short* __restrict__ qb,
                                                  const unsigned short* __restrict__ kb,
                                                  const unsigned short* __restrict__ vtb,
                                                  const unsigned short* __restrict__ maskT,
                                                  const unsigned short* __restrict__ posT,
                                                  unsigned short* __restrict__ attn_out) {
  constexpr int LMD = NN + 8;  // 264 elems; 2-way bank conflict (free)
  __shared__ unsigned short ps[128 * LMD];  // 66 KB
  int qt = blockIdx.x, h = blockIdx.y, bp = blockIdx.z;
  int tid = threadIdx.x, lane = tid & 63, w = tid >> 6;
  int lr = lane & 15, lg = lane >> 4;
  int q0w = qt * 128 + w * 32;  // wave's first q row
  size_t bh = (size_t)(bp * HH + h);
  const unsigned short* Q = qb + bh * NN * HD;
  const unsigned short* K = kb + bh * NN * HD;
  const unsigned short* VT = vtb + bh * HD * NN;
  // Q fragments: 2 chains x 2 k-halves
  short8_t qf0[2], qf1[2];
#pragma unroll
  for (int c = 0; c < 2; ++c) {
    qf0[c] = *(const short8_t*)&Q[(size_t)(q0w + c * 16 + lr) * HD + lg * 8];
    qf1[c] = *(const short8_t*)&Q[(size_t)(q0w + c * 16 + lr) * HD + 32 + lg * 8];
  }
  // prefetch packed mask/pos for the wave's 8 rows (2 chains x 4)
  unsigned mbits[2][4];
  short8_t pv0[2][4], pv1[2][4];
#pragma unroll
  for (int c = 0; c < 2; ++c)
#pragma unroll
    for (int r2 = 0; r2 < 4; ++r2) {
      int qrow = q0w + c * 16 + lg * 4 + r2;
      mbits[c][r2] = maskT[((size_t)bp * NN + qrow) * 16 + lr];
      const unsigned short* pp = &posT[(((size_t)h * NN + qrow) * 16 + lr) * 16];
      pv0[c][r2] = *(const short8_t*)&pp[0];
      pv1[c][r2] = *(const short8_t*)&pp[8];
    }
  // QK^T: each K fragment pair feeds BOTH chains (load:MFMA = 1:2)
  f32x4_t sc[2][16] = {};
#pragma unroll
  for (int f = 0; f < 16; ++f) {
    short8_t b0 = *(const short8_t*)&K[(size_t)(f * 16 + lr) * HD + lg * 8];
    short8_t b1 = *(const short8_t*)&K[(size_t)(f * 16 + lr) * HD + 32 + lg * 8];
    sc[0][f] = __builtin_amdgcn_mfma_f32_16x16x32_bf16(qf0[0], b0, sc[0][f], 0, 0, 0);
    sc[1][f] = __builtin_amdgcn_mfma_f32_16x16x32_bf16(qf0[1], b0, sc[1][f], 0, 0, 0);
    sc[0][f] = __builtin_amdgcn_mfma_f32_16x16x32_bf16(qf1[0], b1, sc[0][f], 0, 0, 0);
    sc[1][f] = __builtin_amdgcn_mfma_f32_16x16x32_bf16(qf1[1], b1, sc[1][f], 0, 0, 0);
  }
  // mask + pos + softmax (scale pre-folded into Q)
#pragma unroll
  for (int c = 0; c < 2; ++c)
#pragma unroll
    for (int r2 = 0; r2 < 4; ++r2) {
      float mx = -3.0e38f;
#pragma unroll
      for (int f = 0; f < 16; ++f) {
        float pw = bf2f((unsigned short)((f < 8) ? pv0[c][r2][f] : pv1[c][r2][f - 8]));
        float s = ((mbits[c][r2] >> f) & 1) ? (sc[c][f][r2] + pw) : -1.0e9f;
        sc[c][f][r2] = s;
        mx = fmaxf(mx, s);
      }
      for (int d2 = 1; d2 < 16; d2 <<= 1) mx = fmaxf(mx, __shfl_xor(mx, d2));
      float sum = 0.f;
#pragma unroll
      for (int f = 0; f < 16; ++f) { float e = __expf(sc[c][f][r2] - mx); sc[c][f][r2] = e; sum += e; }
      for (int d2 = 1; d2 < 16; d2 <<= 1) sum += __shfl_xor(sum, d2);
      float inv = 1.f / sum;
      int prow = w * 32 + c * 16 + lg * 4 + r2;
#pragma unroll
      for (int f = 0; f < 16; ++f) ps[prow * LMD + f * 16 + lr] = f2bf(sc[c][f][r2] * inv);
    }
  // PV: each VT fragment feeds both chains; P rows wave-private (no block barrier)
  f32x4_t ao[2][4] = {};
#pragma unroll
  for (int kt = 0; kt < 8; ++kt) {
    short8_t a0 = *(const short8_t*)&ps[(w * 32 + lr) * LMD + kt * 32 + lg * 8];
    short8_t a1 = *(const short8_t*)&ps[(w * 32 + 16 + lr) * LMD + kt * 32 + lg * 8];
#pragma unroll
    for (int f = 0; f < 4; ++f) {
      short8_t b = *(const short8_t*)&VT[(size_t)(f * 16 + lr) * NN + kt * 32 + lg * 8];
      ao[0][f] = __builtin_amdgcn_mfma_f32_16x16x32_bf16(a0, b, ao[0][f], 0, 0, 0);
      ao[1][f] = __builtin_amdgcn_mfma_f32_16x16x32_bf16(a1, b, ao[1][f], 0, 0, 0);
    }
  }
#pragma unroll
  for (int c = 0; c < 2; ++c)
#pragma unroll
    for (int f = 0; f < 4; ++f)
#pragma unroll
      for (int r2 = 0; r2 < 4; ++r2) {
        int token = bp * NN + q0w + c * 16 + lg * 4 + r2;
        int d = f * 16 + lr;
        attn_out[(size_t)token * CC + h * HD + d] = f2bf(ao[c][f][r2]);
      }
}

extern "C" void kernel_launch(void* const* d_in, const int* in_sizes, int n_in,
                              void* d_out, int out_size, void* d_ws, size_t ws_size,
                              hipStream_t stream) {
  const float* x      = (const float*)d_in[0];
  const int*   mask   = (const int*)d_in[1];
  const float* pos    = (const float*)d_in[2];
  const float* n1w    = (const float*)d_in[3];
  const float* n1b    = (const float*)d_in[4];
  const float* qkv_w  = (const float*)d_in[5];
  const float* qkv_b  = (const float*)d_in[6];
  const float* proj_w = (const float*)d_in[7];
  const float* proj_b = (const float*)d_in[8];
  const float* n2w    = (const float*)d_in[9];
  const float* n2b    = (const float*)d_in[10];
  const float* w1     = (const float*)d_in[11];
  const float* b1     = (const float*)d_in[12];
  const float* w2     = (const float*)d_in[13];
  const float* b2     = (const float*)d_in[14];
  float* out = (float*)d_out;
  char* ws = (char*)d_ws;

  size_t off = 0;
  auto alloc = [&](size_t bytes) { size_t o = off; off += (bytes + 255) & ~(size_t)255; return o; };
  unsigned short* wqkv  = (unsigned short*)(ws + alloc((size_t)3 * CC * CC * 2));
  unsigned short* wproj = (unsigned short*)(ws + alloc((size_t)CC * CC * 2));
  unsigned short* wm1   = (unsigned short*)(ws + alloc((size_t)MLPD * CC * 2));
  unsigned short* wm2   = (unsigned short*)(ws + alloc((size_t)CC * MLPD * 2));
  unsigned short* maskT = (unsigned short*)(ws + alloc((size_t)BP * NN * 16 * 2));     // 1 MB
  unsigned short* posT  = (unsigned short*)(ws + alloc((size_t)HH * NN * NN * 2));     // 1 MB
  unsigned short* xn    = (unsigned short*)(ws + alloc((size_t)MTOT * CC * 2));   // 32 MB
  unsigned short* x1b   = (unsigned short*)(ws + alloc((size_t)MTOT * CC * 2));   // 32 MB bf16 residual
  size_t region = alloc((size_t)MTOT * MLPD * 2);                                 // 128 MB shared region
  const size_t BUFE = (size_t)MTOT * CC;  // elems per 32MB buffer
  unsigned short* qbuf  = (unsigned short*)(ws + region);
  unsigned short* kbuf  = qbuf + BUFE;
  unsigned short* vtbuf = qbuf + 2 * BUFE;
  unsigned short* attnb = qbuf + 3 * BUFE;
  unsigned short* hbuf  = (unsigned short*)(ws + region);  // reuses all 4 (dead by MLP time)

  // fused prologue: weight converts + mask/pos packs (one launch)
  k_prep<<<2048, 256, 0, stream>>>(qkv_w, proj_w, w1, w2, mask, pos,
                                   wqkv, wproj, wm1, wm2, maskT, posT);

  // norm1 (f32 input)
  k_gn<0><<<BP * 2, 256, 0, stream>>>(x, n1w, n1b, xn);
  // qkv = xn @ qkv_w^T + b, split-stored into q(*scale)/k/v^T head-major buffers
  k_gemm<3><<<dim3(3 * CC / 128, MTOT / 128), 256, 0, stream>>>(xn, wqkv, qkv_b, nullptr, nullptr, nullptr, nullptr, qbuf, kbuf, vtbuf, MTOT, 3 * CC, CC);
  // attention
  k_attn4<<<dim3(2, HH, BP), 256, 0, stream>>>(qbuf, kbuf, vtbuf, maskT, posT, attnb);
  // x1b = bf16(x + attn @ proj_w^T + proj_b)
  k_gemm<2><<<dim3(CC / 128, MTOT / 128), 256, 0, stream>>>(attnb, wproj, proj_b, x, nullptr, x1b, nullptr, nullptr, nullptr, nullptr, MTOT, CC, CC);
  // norm2 (bf16 input)
  k_gn<1><<<BP * 2, 256, 0, stream>>>(x1b, n2w, n2b, xn);
  // h = gelu(xn @ w1^T + b1)
  k_gemm<1><<<dim3(MLPD / 128, MTOT / 128), 256, 0, stream>>>(xn, wm1, b1, nullptr, nullptr, hbuf, nullptr, nullptr, nullptr, nullptr, MTOT, MLPD, CC);
  // out = x1b + h @ w2^T + b2  (f32 output)
  k_gemm<5><<<dim3(CC / 128, MTOT / 128), 256, 0, stream>>>(hbuf, wm2, b2, nullptr, x1b, nullptr, out, nullptr, nullptr, nullptr, MTOT, CC, MLPD);
}

// Round 19
// 450.861 us; speedup vs baseline: 1.1618x; 1.0649x over previous
//
#include <hip/hip_runtime.h>
#include <hip/hip_bf16.h>

// Problem constants
constexpr int BB = 2, PP = 64, NN = 256, CC = 512, HH = 8, HD = 64, MLPD = 2048;
constexpr int BP = BB * PP;       // 128
constexpr int MTOT = BP * NN;     // 32768
constexpr float EPS = 1e-5f;

typedef __attribute__((ext_vector_type(8))) short short8_t;
typedef __attribute__((ext_vector_type(4))) short short4_t;
typedef __attribute__((ext_vector_type(4))) float f32x4_t;
typedef __attribute__((ext_vector_type(2))) unsigned int uint2_t;

__device__ inline unsigned short f2bf(float f) {
  union { float f; unsigned u; } v; v.f = f;
  unsigned r = v.u + 0x7fffu + ((v.u >> 16) & 1u);
  return (unsigned short)(r >> 16);
}
__device__ inline float bf2f(unsigned short u) {
  union { unsigned u; float f; } v; v.u = ((unsigned)u) << 16;
  return v.f;
}
// pack 2 f32 -> 2 bf16 in one dword (RNE), gfx950 HW op
__device__ inline unsigned int cvt_pk_bf16(float lo, float hi) {
  unsigned int r;
  asm("v_cvt_pk_bf16_f32 %0, %1, %2" : "=v"(r) : "v"(lo), "v"(hi));
  return r;
}

// async 16B global -> LDS (wave-uniform LDS base, per-lane global addr; HW writes base + lane*16)
__device__ inline void async_copy16(unsigned short* lds_base, const unsigned short* g) {
  __builtin_amdgcn_global_load_lds((const __attribute__((address_space(1))) unsigned int*)g,
                                   (__attribute__((address_space(3))) unsigned int*)lds_base,
                                   16, 0, 0);
}

// cheap exact-enough gelu: tanh form, err<~5e-4 abs (bf16 output)
__device__ inline float gelu_fast(float v) {
  float vc = fminf(fmaxf(v, -8.f), 8.f);
  float e = __expf(1.5957691216f * vc + 0.071354816f * vc * vc * vc);
  return v * e * __builtin_amdgcn_rcpf(e + 1.f);
}

// ---------------- fused prologue: weight converts + mask/pos packs in ONE launch ----------------
constexpr int N_QKVW = 3 * CC * CC;          // 786432
constexpr int N_PROJW = CC * CC;             // 262144
constexpr int N_W1 = MLPD * CC;              // 1048576
constexpr int N_W2 = CC * MLPD;              // 1048576
constexpr int N_MASK = BP * NN * 16;         // 524288
constexpr int N_POS = HH * NN * NN;          // 524288
constexpr int C1 = N_QKVW;
constexpr int C2 = C1 + N_PROJW;
constexpr int C3 = C2 + N_W1;
constexpr int C4 = C3 + N_W2;
constexpr int C5 = C4 + N_MASK;
constexpr int C6 = C5 + N_POS;               // 4194304

__global__ void k_prep(const float* __restrict__ qkv_w, const float* __restrict__ proj_w,
                       const float* __restrict__ w1, const float* __restrict__ w2,
                       const int* __restrict__ mask, const float* __restrict__ pos,
                       unsigned short* __restrict__ wqkv, unsigned short* __restrict__ wproj,
                       unsigned short* __restrict__ wm1, unsigned short* __restrict__ wm2,
                       unsigned short* __restrict__ mt, unsigned short* __restrict__ pt) {
  int stride = gridDim.x * blockDim.x;
  for (int idx = blockIdx.x * blockDim.x + threadIdx.x; idx < C6; idx += stride) {
    if (idx < C1) {
      wqkv[idx] = f2bf(qkv_w[idx]);
    } else if (idx < C2) {
      int i = idx - C1; wproj[i] = f2bf(proj_w[i]);
    } else if (idx < C3) {
      int i = idx - C2; wm1[i] = f2bf(w1[i]);
    } else if (idx < C4) {
      int i = idx - C3; wm2[i] = f2bf(w2[i]);
    } else if (idx < C5) {
      int i = idx - C4;
      int lr = i & 15;
      int row = (i >> 4) & 255;
      int bp = i >> 12;
      const int* mp = mask + ((size_t)bp * NN + row) * NN;
      unsigned v = 0;
#pragma unroll
      for (int f = 0; f < 16; ++f) v |= (unsigned)(mp[f * 16 + lr] > 0) << f;
      mt[i] = (unsigned short)v;
    } else {
      int i = idx - C5;
      int f = i & 15;
      int lr = (i >> 4) & 15;
      int row = (i >> 8) & 255;
      int h = i >> 16;
      pt[i] = f2bf(pos[((size_t)h * NN + row) * NN + f * 16 + lr]);
    }
  }
}

// ---------------- group norm over N (tokens), per (bp, c); IN=0 f32 input, IN=1 bf16 input ----
template <int IN>
__global__ void k_gn(const void* __restrict__ xin, const float* __restrict__ w,
                     const float* __restrict__ b, unsigned short* __restrict__ out) {
  int bp = blockIdx.x >> 1;
  int c = ((blockIdx.x & 1) << 8) + threadIdx.x;
  float s = 0.f, sq = 0.f;
  const float* xf = (const float*)xin + (size_t)bp * NN * CC + c;
  const unsigned short* xb = (const unsigned short*)xin + (size_t)bp * NN * CC + c;
  for (int n = 0; n < NN; ++n) {
    float v = (IN == 0) ? xf[(size_t)n * CC] : bf2f(xb[(size_t)n * CC]);
    s += v; sq += v * v;
  }
  float mean = s * (1.f / NN);
  float var = sq * (1.f / NN) - mean * mean;
  float rstd = rsqrtf(var + EPS);
  float ww = w[c], bb = b[c];
  unsigned short* op = out + (size_t)bp * NN * CC + c;
  for (int n = 0; n < NN; ++n) {
    float v = (IN == 0) ? xf[(size_t)n * CC] : bf2f(xb[(size_t)n * CC]);
    op[(size_t)n * CC] = f2bf((v - mean) * rstd * ww + bb);
  }
}

// ---------------- bf16 MFMA GEMM: 8 waves x (64x32), single-buffer, T1 XCD swizzle ----
// C = A @ B^T + bias. A[M][K], Bw[Nn][K] row-major bf16. 512 threads; acc[4][2] keeps
// VGPR low -> 4 blocks/CU = 32 waves/CU (HW max) to hide the barrier drains.
// EPI 1/2/5 swapped-operand epilogue (lane holds row m, 4 consecutive cols).
// EPI 3 qkv split-store (unswapped): Q(*0.125) -> qb, K -> kb, V -> vtb[bp*H+h][d][m]
template <int EPI>
__global__ __launch_bounds__(512) void k_gemm(const unsigned short* __restrict__ A,
                                              const unsigned short* __restrict__ Bw,
                                              const float* __restrict__ bias,
                                              const float* __restrict__ resid,
                                              const unsigned short* __restrict__ residb,
                                              unsigned short* __restrict__ outb,
                                              float* __restrict__ outf,
                                              unsigned short* __restrict__ qb,
                                              unsigned short* __restrict__ kb,
                                              unsigned short* __restrict__ vtb,
                                              int M, int Nn, int K) {
  constexpr bool SW = (EPI != 3);
  constexpr int BM = 128, BN = 128, BK = 64;
  __shared__ unsigned short As[BM * BK];  // 16 KB, linear
  __shared__ unsigned short Bs[BN * BK];  // 16 KB, linear
  int tid = threadIdx.x;
  int lane = tid & 63, w = tid >> 6;      // 8 waves
  int wm = w >> 2, wn = w & 3;            // 2M x 4N; per-wave out 64x32
  // T1 XCD-chunk swizzle (all grids have nwg % 8 == 0)
  int nwgx = gridDim.x;
  int nwg = nwgx * gridDim.y;
  int linear = blockIdx.y * nwgx + blockIdx.x;
  int cpx = nwg >> 3;
  int swz = (linear & 7) * cpx + (linear >> 3);
  int bx = swz % nwgx, by = swz / nwgx;
  int m0 = by * BM, n0 = bx * BN;
  int rowc = lane >> 3;
  int csrc = (lane & 7) ^ (rowc & 7);
  int lr = lane & 15, lg = lane >> 4;
  f32x4_t acc[4][2] = {};
  for (int k0 = 0; k0 < K; k0 += BK) {
#pragma unroll
    for (int it = 0; it < 2; ++it) {
      int chunk = w * 2 + it;             // 0..15
      int grow = chunk * 8 + rowc;        // 0..127
      async_copy16(&As[chunk * 512], &A[(size_t)(m0 + grow) * K + k0 + csrc * 8]);
      async_copy16(&Bs[chunk * 512], &Bw[(size_t)(n0 + grow) * K + k0 + csrc * 8]);
    }
    __syncthreads();
#pragma unroll
    for (int kk = 0; kk < BK; kk += 32) {
      int kslot = (kk >> 3) + lg;
      short8_t af[4], bfr[2];
#pragma unroll
      for (int i = 0; i < 4; ++i) {
        int r = wm * 64 + i * 16 + lr;
        af[i] = *(const short8_t*)&As[r * 64 + ((kslot ^ (r & 7)) * 8)];
      }
#pragma unroll
      for (int j = 0; j < 2; ++j) {
        int r = wn * 32 + j * 16 + lr;
        bfr[j] = *(const short8_t*)&Bs[r * 64 + ((kslot ^ (r & 7)) * 8)];
      }
#pragma unroll
      for (int i = 0; i < 4; ++i)
#pragma unroll
        for (int j = 0; j < 2; ++j) {
          if (SW)
            acc[i][j] = __builtin_amdgcn_mfma_f32_16x16x32_bf16(bfr[j], af[i], acc[i][j], 0, 0, 0);
          else
            acc[i][j] = __builtin_amdgcn_mfma_f32_16x16x32_bf16(af[i], bfr[j], acc[i][j], 0, 0, 0);
        }
    }
    __syncthreads();
  }
  if (SW) {
    // lane holds row m = m0+wm*64+i*16+lr, cols n0c..n0c+3 with n0c = n0+wn*32+j*16+lg*4
#pragma unroll
    for (int i = 0; i < 4; ++i) {
      int m = m0 + wm * 64 + i * 16 + lr;
#pragma unroll
      for (int j = 0; j < 2; ++j) {
        int n0c = n0 + wn * 32 + j * 16 + lg * 4;
        f32x4_t bv = *(const f32x4_t*)&bias[n0c];
        size_t off = (size_t)m * Nn + n0c;
        if (EPI == 1) {
          float g0 = gelu_fast(acc[i][j][0] + bv[0]);
          float g1 = gelu_fast(acc[i][j][1] + bv[1]);
          float g2 = gelu_fast(acc[i][j][2] + bv[2]);
          float g3 = gelu_fast(acc[i][j][3] + bv[3]);
          uint2_t pk;
          pk[0] = cvt_pk_bf16(g0, g1);
          pk[1] = cvt_pk_bf16(g2, g3);
          *(uint2_t*)&outb[off] = pk;
        } else if (EPI == 2) {
          f32x4_t rv = *(const f32x4_t*)&resid[off];
          uint2_t pk;
          pk[0] = cvt_pk_bf16(rv[0] + acc[i][j][0] + bv[0], rv[1] + acc[i][j][1] + bv[1]);
          pk[1] = cvt_pk_bf16(rv[2] + acc[i][j][2] + bv[2], rv[3] + acc[i][j][3] + bv[3]);
          *(uint2_t*)&outb[off] = pk;
        } else {  // EPI == 5
          short4_t rv = *(const short4_t*)&residb[off];
          f32x4_t o;
#pragma unroll
          for (int r2 = 0; r2 < 4; ++r2)
            o[r2] = bf2f((unsigned short)rv[r2]) + acc[i][j][r2] + bv[r2];
          *(f32x4_t*)&outf[off] = o;
        }
      }
    }
  } else {
    // EPI == 3, unswapped: lane holds col = ...+lr, rows row0..row0+3
#pragma unroll
    for (int i = 0; i < 4; ++i)
#pragma unroll
      for (int j = 0; j < 2; ++j) {
        int col = n0 + wn * 32 + j * 16 + lr;
        float bv = bias[col];
        int row0 = m0 + wm * 64 + i * 16 + lg * 4;
        int which = col >> 9;         // 0=q 1=k 2=v (wave-uniform)
        int hh2 = (col >> 6) & 7;     // head (uniform within 16-col group)
        int d = col & 63;
        int bp_ = row0 >> 8, m = row0 & 255;
        size_t hb = (size_t)(bp_ * HH + hh2);
        if (which == 2) {
          short4_t pk;
#pragma unroll
          for (int r2 = 0; r2 < 4; ++r2) pk[r2] = (short)f2bf(acc[i][j][r2] + bv);
          *(short4_t*)&vtb[(hb * HD + d) * NN + m] = pk;
        } else if (which == 0) {
#pragma unroll
          for (int r2 = 0; r2 < 4; ++r2)
            qb[(hb * NN + m + r2) * HD + d] = f2bf((acc[i][j][r2] + bv) * 0.125f);
        } else {
#pragma unroll
          for (int r2 = 0; r2 < 4; ++r2)
            kb[(hb * NN + m + r2) * HD + d] = f2bf(acc[i][j][r2] + bv);
        }
      }
  }
}

// ---------------- fused attention v4: 2 q-chains per wave (K/V fragment reuse) -------
// grid: (2, H, BP); 256 threads = 4 waves; wave owns 32 q-rows = 2 independent 16-row chains.
__global__ __launch_bounds__(256, 2) void k_attn4(const unsigned short* __restrict__ qb,
                                                  const unsigned short* __restrict__ kb,
                                                  const unsigned short* __restrict__ vtb,
                                                  const unsigned short* __restrict__ maskT,
                                                  const unsigned short* __restrict__ posT,
                                                  unsigned short* __restrict__ attn_out) {
  constexpr int LMD = NN + 8;  // 264 elems; 2-way bank conflict (free)
  __shared__ unsigned short ps[128 * LMD];  // 66 KB
  int qt = blockIdx.x, h = blockIdx.y, bp = blockIdx.z;
  int tid = threadIdx.x, lane = tid & 63, w = tid >> 6;
  int lr = lane & 15, lg = lane >> 4;
  int q0w = qt * 128 + w * 32;  // wave's first q row
  size_t bh = (size_t)(bp * HH + h);
  const unsigned short* Q = qb + bh * NN * HD;
  const unsigned short* K = kb + bh * NN * HD;
  const unsigned short* VT = vtb + bh * HD * NN;
  // Q fragments: 2 chains x 2 k-halves
  short8_t qf0[2], qf1[2];
#pragma unroll
  for (int c = 0; c < 2; ++c) {
    qf0[c] = *(const short8_t*)&Q[(size_t)(q0w + c * 16 + lr) * HD + lg * 8];
    qf1[c] = *(const short8_t*)&Q[(size_t)(q0w + c * 16 + lr) * HD + 32 + lg * 8];
  }
  // prefetch packed mask/pos for the wave's 8 rows (2 chains x 4)
  unsigned mbits[2][4];
  short8_t pv0[2][4], pv1[2][4];
#pragma unroll
  for (int c = 0; c < 2; ++c)
#pragma unroll
    for (int r2 = 0; r2 < 4; ++r2) {
      int qrow = q0w + c * 16 + lg * 4 + r2;
      mbits[c][r2] = maskT[((size_t)bp * NN + qrow) * 16 + lr];
      const unsigned short* pp = &posT[(((size_t)h * NN + qrow) * 16 + lr) * 16];
      pv0[c][r2] = *(const short8_t*)&pp[0];
      pv1[c][r2] = *(const short8_t*)&pp[8];
    }
  // QK^T: each K fragment pair feeds BOTH chains (load:MFMA = 1:2)
  f32x4_t sc[2][16] = {};
#pragma unroll
  for (int f = 0; f < 16; ++f) {
    short8_t b0 = *(const short8_t*)&K[(size_t)(f * 16 + lr) * HD + lg * 8];
    short8_t b1 = *(const short8_t*)&K[(size_t)(f * 16 + lr) * HD + 32 + lg * 8];
    sc[0][f] = __builtin_amdgcn_mfma_f32_16x16x32_bf16(qf0[0], b0, sc[0][f], 0, 0, 0);
    sc[1][f] = __builtin_amdgcn_mfma_f32_16x16x32_bf16(qf0[1], b0, sc[1][f], 0, 0, 0);
    sc[0][f] = __builtin_amdgcn_mfma_f32_16x16x32_bf16(qf1[0], b1, sc[0][f], 0, 0, 0);
    sc[1][f] = __builtin_amdgcn_mfma_f32_16x16x32_bf16(qf1[1], b1, sc[1][f], 0, 0, 0);
  }
  // mask + pos + softmax (scale pre-folded into Q)
#pragma unroll
  for (int c = 0; c < 2; ++c)
#pragma unroll
    for (int r2 = 0; r2 < 4; ++r2) {
      float mx = -3.0e38f;
#pragma unroll
      for (int f = 0; f < 16; ++f) {
        float pw = bf2f((unsigned short)((f < 8) ? pv0[c][r2][f] : pv1[c][r2][f - 8]));
        float s = ((mbits[c][r2] >> f) & 1) ? (sc[c][f][r2] + pw) : -1.0e9f;
        sc[c][f][r2] = s;
        mx = fmaxf(mx, s);
      }
      for (int d2 = 1; d2 < 16; d2 <<= 1) mx = fmaxf(mx, __shfl_xor(mx, d2));
      float sum = 0.f;
#pragma unroll
      for (int f = 0; f < 16; ++f) { float e = __expf(sc[c][f][r2] - mx); sc[c][f][r2] = e; sum += e; }
      for (int d2 = 1; d2 < 16; d2 <<= 1) sum += __shfl_xor(sum, d2);
      float inv = 1.f / sum;
      int prow = w * 32 + c * 16 + lg * 4 + r2;
#pragma unroll
      for (int f = 0; f < 16; ++f) ps[prow * LMD + f * 16 + lr] = f2bf(sc[c][f][r2] * inv);
    }
  // PV: each VT fragment feeds both chains; P rows wave-private (no block barrier)
  f32x4_t ao[2][4] = {};
#pragma unroll
  for (int kt = 0; kt < 8; ++kt) {
    short8_t a0 = *(const short8_t*)&ps[(w * 32 + lr) * LMD + kt * 32 + lg * 8];
    short8_t a1 = *(const short8_t*)&ps[(w * 32 + 16 + lr) * LMD + kt * 32 + lg * 8];
#pragma unroll
    for (int f = 0; f < 4; ++f) {
      short8_t b = *(const short8_t*)&VT[(size_t)(f * 16 + lr) * NN + kt * 32 + lg * 8];
      ao[0][f] = __builtin_amdgcn_mfma_f32_16x16x32_bf16(a0, b, ao[0][f], 0, 0, 0);
      ao[1][f] = __builtin_amdgcn_mfma_f32_16x16x32_bf16(a1, b, ao[1][f], 0, 0, 0);
    }
  }
#pragma unroll
  for (int c = 0; c < 2; ++c)
#pragma unroll
    for (int f = 0; f < 4; ++f)
#pragma unroll
      for (int r2 = 0; r2 < 4; ++r2) {
        int token = bp * NN + q0w + c * 16 + lg * 4 + r2;
        int d = f * 16 + lr;
        attn_out[(size_t)token * CC + h * HD + d] = f2bf(ao[c][f][r2]);
      }
}

extern "C" void kernel_launch(void* const* d_in, const int* in_sizes, int n_in,
                              void* d_out, int out_size, void* d_ws, size_t ws_size,
                              hipStream_t stream) {
  const float* x      = (const float*)d_in[0];
  const int*   mask   = (const int*)d_in[1];
  const float* pos    = (const float*)d_in[2];
  const float* n1w    = (const float*)d_in[3];
  const float* n1b    = (const float*)d_in[4];
  const float* qkv_w  = (const float*)d_in[5];
  const float* qkv_b  = (const float*)d_in[6];
  const float* proj_w = (const float*)d_in[7];
  const float* proj_b = (const float*)d_in[8];
  const float* n2w    = (const float*)d_in[9];
  const float* n2b    = (const float*)d_in[10];
  const float* w1     = (const float*)d_in[11];
  const float* b1     = (const float*)d_in[12];
  const float* w2     = (const float*)d_in[13];
  const float* b2     = (const float*)d_in[14];
  float* out = (float*)d_out;
  char* ws = (char*)d_ws;

  size_t off = 0;
  auto alloc = [&](size_t bytes) { size_t o = off; off += (bytes + 255) & ~(size_t)255; return o; };
  unsigned short* wqkv  = (unsigned short*)(ws + alloc((size_t)3 * CC * CC * 2));
  unsigned short* wproj = (unsigned short*)(ws + alloc((size_t)CC * CC * 2));
  unsigned short* wm1   = (unsigned short*)(ws + alloc((size_t)MLPD * CC * 2));
  unsigned short* wm2   = (unsigned short*)(ws + alloc((size_t)CC * MLPD * 2));
  unsigned short* maskT = (unsigned short*)(ws + alloc((size_t)BP * NN * 16 * 2));     // 1 MB
  unsigned short* posT  = (unsigned short*)(ws + alloc((size_t)HH * NN * NN * 2));     // 1 MB
  unsigned short* xn    = (unsigned short*)(ws + alloc((size_t)MTOT * CC * 2));   // 32 MB
  unsigned short* x1b   = (unsigned short*)(ws + alloc((size_t)MTOT * CC * 2));   // 32 MB bf16 residual
  size_t region = alloc((size_t)MTOT * MLPD * 2);                                 // 128 MB shared region
  const size_t BUFE = (size_t)MTOT * CC;  // elems per 32MB buffer
  unsigned short* qbuf  = (unsigned short*)(ws + region);
  unsigned short* kbuf  = qbuf + BUFE;
  unsigned short* vtbuf = qbuf + 2 * BUFE;
  unsigned short* attnb = qbuf + 3 * BUFE;
  unsigned short* hbuf  = (unsigned short*)(ws + region);  // reuses all 4 (dead by MLP time)

  // fused prologue: weight converts + mask/pos packs (one launch)
  k_prep<<<2048, 256, 0, stream>>>(qkv_w, proj_w, w1, w2, mask, pos,
                                   wqkv, wproj, wm1, wm2, maskT, posT);

  // norm1 (f32 input)
  k_gn<0><<<BP * 2, 256, 0, stream>>>(x, n1w, n1b, xn);
  // qkv = xn @ qkv_w^T + b, split-stored into q(*scale)/k/v^T head-major buffers
  k_gemm<3><<<dim3(3 * CC / 128, MTOT / 128), 512, 0, stream>>>(xn, wqkv, qkv_b, nullptr, nullptr, nullptr, nullptr, qbuf, kbuf, vtbuf, MTOT, 3 * CC, CC);
  // attention
  k_attn4<<<dim3(2, HH, BP), 256, 0, stream>>>(qbuf, kbuf, vtbuf, maskT, posT, attnb);
  // x1b = bf16(x + attn @ proj_w^T + proj_b)
  k_gemm<2><<<dim3(CC / 128, MTOT / 128), 512, 0, stream>>>(attnb, wproj, proj_b, x, nullptr, x1b, nullptr, nullptr, nullptr, nullptr, MTOT, CC, CC);
  // norm2 (bf16 input)
  k_gn<1><<<BP * 2, 256, 0, stream>>>(x1b, n2w, n2b, xn);
  // h = gelu(xn @ w1^T + b1)
  k_gemm<1><<<dim3(MLPD / 128, MTOT / 128), 512, 0, stream>>>(xn, wm1, b1, nullptr, nullptr, hbuf, nullptr, nullptr, nullptr, nullptr, MTOT, MLPD, CC);
  // out = x1b + h @ w2^T + b2  (f32 output)
  k_gemm<5><<<dim3(CC / 128, MTOT / 128), 512, 0, stream>>>(hbuf, wm2, b2, nullptr, x1b, nullptr, out, nullptr, nullptr, nullptr, MTOT, CC, MLPD);
}